// Round 10
// baseline (143.446 us; speedup 1.0000x reference)
//
#include <hip/hip_runtime.h>
#include <stdint.h>

typedef unsigned short u16;
typedef __attribute__((ext_vector_type(8))) short short8;
typedef __attribute__((ext_vector_type(4))) float f32x4;

#define B_      16
#define L_      1024
#define H_      1024
#define G_      128
#define M_TOT   16368            // B*(L-1)
#define K_TOT   3072
#define OUT_SEG 2095104          // M_TOT*G_
#define KL_IDX  (4*OUT_SEG)
#define KL_BLOCKS 4092           // M_TOT / 4 exactly
#define NKT     96               // K_TOT / 32

// ws layout
#define WS_WT_OFF    0           // bf16 W'T [512][3072] = 3,145,728 B
#define WS_BIAS_OFF  3145728     // float[512]
#define WS_PART_OFF  3147776     // float[4092] block partials

__device__ inline u16 f2bf(float f) {
    union { float f; uint32_t u; } x; x.f = f;
    uint32_t u = x.u;
    return (u16)((u + 0x7fffu + ((u >> 16) & 1u)) >> 16);
}

__device__ inline void gload16(const void* g, void* l) {
    __builtin_amdgcn_global_load_lds(
        (const __attribute__((address_space(1))) void*)g,
        (__attribute__((address_space(3))) void*)l, 16, 0, 0);
}

__device__ inline short8 cvt8(f32x4 x, f32x4 y) {
    union { short8 s; uint32_t u[4]; } r;
    asm("v_cvt_pk_bf16_f32 %0, %1, %2" : "=v"(r.u[0]) : "v"(x[0]), "v"(x[1]));
    asm("v_cvt_pk_bf16_f32 %0, %1, %2" : "=v"(r.u[1]) : "v"(x[2]), "v"(x[3]));
    asm("v_cvt_pk_bf16_f32 %0, %1, %2" : "=v"(r.u[2]) : "v"(y[0]), "v"(y[1]));
    asm("v_cvt_pk_bf16_f32 %0, %1, %2" : "=v"(r.u[3]) : "v"(y[2]), "v"(y[3]));
    return r.s;
}

// ---------------- prep: build W'T (bf16, [512][3072]) + bias[512] ------------
__global__ __launch_bounds__(256) void prep_kernel(
    const float* __restrict__ Wzm, const float* __restrict__ bzm,
    const float* __restrict__ Wzv, const float* __restrict__ bzv,
    const float* __restrict__ Wqm, const float* __restrict__ bqm,
    const float* __restrict__ Wqv, const float* __restrict__ bqv,
    u16* __restrict__ wt, float* __restrict__ bias)
{
    int n = blockIdx.x;                 // 0..511 (output column)
    int tid = threadIdx.x;
    const float* W; const float* bsrc; int g; int kmax;
    if (n < 128)      { W = Wzm; bsrc = bzm; g = n;       kmax = 2048; }
    else if (n < 256) { W = Wzv; bsrc = bzv; g = n - 128; kmax = 2048; }
    else if (n < 384) { W = Wqm; bsrc = bqm; g = n - 256; kmax = 3072; }
    else              { W = Wqv; bsrc = bqv; g = n - 384; kmax = 3072; }
    if (tid == 0) bias[n] = bsrc[g];
    #pragma unroll
    for (int i = 0; i < 12; ++i) {
        int k = i * 256 + tid;
        float v = (k < kmax) ? W[(size_t)k * G_ + g] : 0.0f;
        wt[(size_t)n * K_TOT + k] = f2bf(v);
    }
}

// ---------------- GEMM: out[m, 0:512] = ce @ W' + bias ----------------------
// BM=64, BN=128, BK=32, 4 waves (2x2 of 32x64), 1024 blocks -> 3 blocks/CU
// (LDS 48KB), 12 waves/CU. 3-deep LDS ring, ALL staging via global_load_lds
// (A fp32 + B bf16), source-preswizzled. Raw s_barrier + counted vmcnt(8):
// 2 stages always in flight; NO vmcnt(0) drain in the main loop.
// s_setprio(1) around the MFMA cluster (T5).
// A swizzle (8 chunks of 16B per 128B row): chunk ^= (r&7).
// B swizzle (4 slots of 16B per 64B row):  slot  ^= (n>>1)&3.
__global__ __launch_bounds__(256, 3) void gemm_kernel(
    const float* __restrict__ events, const float* __restrict__ contexts,
    const u16* __restrict__ wt, const float* __restrict__ bias,
    float* __restrict__ out)
{
    __shared__ float Af[3][64 * 32];    // fp32 A tiles, swizzled (8 KB each)
    __shared__ u16   Bs[3][128 * 32];   // bf16 B tiles, swizzled (8 KB each)

    const int tid  = threadIdx.x;
    const int bid  = blockIdx.x;
    // XCD swizzle: the 4 nb-blocks sharing an A panel land on one XCD.
    const int xcd  = bid & 7;
    const int nb   = (bid >> 3) & 3;
    const int mp   = xcd * 32 + (bid >> 5);   // 0..255
    const int m0   = mp * 64;

    const int lane = tid & 63;
    const int w    = tid >> 6;
    const int wm   = (w >> 1) * 32;
    const int wn   = (w & 1) * 64;
    const int lr   = lane & 15;
    const int kg   = lane >> 4;          // 0..3

    // ---- A staging sources: 2 chunks/thread, chunk c = it*256+tid ->
    //      row r=c>>3 (0..63), dest chunk cd=c&7, source chunk cs=cd^(r&7).
    const float* aS0[2]; const float* aS1[2]; const float* aS2[2];
    #pragma unroll
    for (int it = 0; it < 2; ++it) {
        int c  = it * 256 + tid;
        int r  = c >> 3;
        int cs = (c & 7) ^ (r & 7);
        int m = m0 + r; if (m > M_TOT - 1) m = M_TOT - 1;
        int b = m / 1023;
        int t = m - b * 1023;
        aS0[it] = events   + ((size_t)(b * L_ + t)) * H_ + cs * 4;
        aS1[it] = aS0[it] + H_;
        aS2[it] = contexts + ((size_t)(b * (L_ - 1) + t)) * H_ + cs * 4;
    }
    // ---- B staging sources: 2 chunks/thread, c = it*256+tid ->
    //      row nloc=c>>2, dest slot sd=c&3, source slot ss=sd^((nloc>>1)&3).
    const u16* bS[2];
    #pragma unroll
    for (int it = 0; it < 2; ++it) {
        int c    = it * 256 + tid;
        int nloc = c >> 2;
        int ss   = (c & 3) ^ ((nloc >> 1) & 3);
        bS[it] = wt + (size_t)(nb * 128 + nloc) * K_TOT + ss * 8;
    }

    // ---- fragment read offsets ----
    int aoff[2][2];   // A: float idx = row*32 + ((cw ^ (row&7))<<2), cw=2kg,2kg+1
    int boff[4];      // B: u16 idx = nn*32 + ((kg ^ ((nn>>1)&3))<<3)
    #pragma unroll
    for (int i = 0; i < 2; ++i) {
        int row = wm + i * 16 + lr;
        aoff[i][0] = row * 32 + (((2 * kg)     ^ (row & 7)) << 2);
        aoff[i][1] = row * 32 + (((2 * kg + 1) ^ (row & 7)) << 2);
    }
    #pragma unroll
    for (int j = 0; j < 4; ++j) {
        int nn  = wn + j * 16 + lr;
        boff[j] = nn * 32 + ((kg ^ ((nn >> 1) & 3)) << 3);
    }

    f32x4 acc[2][4];
    #pragma unroll
    for (int i = 0; i < 2; ++i)
        #pragma unroll
        for (int j = 0; j < 4; ++j)
            acc[i][j] = (f32x4){0.f, 0.f, 0.f, 0.f};

    auto stage = [&](int buf, int kt) {
        int k0 = kt * 32;
        int rg = k0 >> 10;               // tiles never straddle source regions
        int kq = k0 & 1023;
        #pragma unroll
        for (int it = 0; it < 2; ++it) {
            const float* s = (rg == 0) ? aS0[it] : (rg == 1 ? aS1[it] : aS2[it]);
            gload16(s + kq, &Af[buf][(it * 256 + tid) * 4]);
        }
        #pragma unroll
        for (int it = 0; it < 2; ++it)
            gload16(bS[it] + k0, &Bs[buf][(it * 256 + tid) * 8]);
    };
    auto compute = [&](int buf) {
        short8 a[2], bf[4];
        #pragma unroll
        for (int i = 0; i < 2; ++i) {
            f32x4 x = *(const f32x4*)&Af[buf][aoff[i][0]];
            f32x4 y = *(const f32x4*)&Af[buf][aoff[i][1]];
            a[i] = cvt8(x, y);
        }
        #pragma unroll
        for (int j = 0; j < 4; ++j)
            bf[j] = *(const short8*)&Bs[buf][boff[j]];
        __builtin_amdgcn_s_setprio(1);
        #pragma unroll
        for (int i = 0; i < 2; ++i)
            #pragma unroll
            for (int j = 0; j < 4; ++j)
                acc[i][j] = __builtin_amdgcn_mfma_f32_16x16x32_bf16(
                    a[i], bf[j], acc[i][j], 0, 0, 0);
        __builtin_amdgcn_s_setprio(0);
    };

#define WAITV(N)                                                               \
    asm volatile("s_waitcnt vmcnt(" #N ")" ::: "memory");                      \
    __builtin_amdgcn_sched_barrier(0);
#define LGKM0                                                                  \
    asm volatile("s_waitcnt lgkmcnt(0)" ::: "memory");                         \
    __builtin_amdgcn_sched_barrier(0);
#define BAR __builtin_amdgcn_s_barrier()

    // prologue: two tiles in flight (8 VMEM/thread outstanding)
    stage(0, 0);
    stage(1, 1);

    for (int t = 0; t < 93; t += 3) {
        stage(2, t + 2); WAITV(8); BAR; compute(0); LGKM0; BAR;
        stage(0, t + 3); WAITV(8); BAR; compute(1); LGKM0; BAR;
        stage(1, t + 4); WAITV(8); BAR; compute(2); LGKM0; BAR;
    }
    // tiles 93, 94, 95
    stage(2, 95); WAITV(8); BAR; compute(0); LGKM0; BAR;
    WAITV(4); BAR; compute(1); LGKM0; BAR;
    WAITV(0); BAR; compute(2);

#undef WAITV
#undef LGKM0
#undef BAR

    // epilogue: C row = wm + i*16 + kg*4 + rr ; col = wn + j*16 + lr
    const float* bptr = bias + nb * 128;
    float* obase = out + (size_t)nb * OUT_SEG;
    #pragma unroll
    for (int i = 0; i < 2; ++i) {
        int mloc = wm + i * 16 + kg * 4;
        #pragma unroll
        for (int j = 0; j < 4; ++j) {
            int g = wn + j * 16 + lr;
            float bv = bptr[g];
            #pragma unroll
            for (int rr = 0; rr < 4; ++rr) {
                int mo = m0 + mloc + rr;
                if (mo < M_TOT) obase[(size_t)mo * G_ + g] = acc[i][j][rr] + bv;
            }
        }
    }
}

// ---------------- KL reduction: stage 1 (per-block partials, no atomics) -----
__global__ __launch_bounds__(256) void kl_kernel(const float* __restrict__ out,
                                                 float* __restrict__ partial)
{
    int wid  = threadIdx.x >> 6;
    int row  = blockIdx.x * 4 + wid;        // M_TOT = 4092*4 exactly
    int lane = threadIdx.x & 63;
    const float* zm  = out;
    const float* zlv = out + OUT_SEG;
    const float* qm  = out + (size_t)2 * OUT_SEG;
    const float* qlv = out + (size_t)3 * OUT_SEG;
    size_t base = (size_t)row * G_;
    float s = 0.f;
    #pragma unroll
    for (int hh = 0; hh < 2; ++hh) {
        int g = lane + hh * 64;
        float a = zm[base + g], b = zlv[base + g];
        float c = qm[base + g], d = qlv[base + g];
        float diff = a - c;
        s += d - b + (__expf(b) + diff * diff) * __expf(-d) - 1.0f;
    }
    #pragma unroll
    for (int off = 32; off > 0; off >>= 1)
        s += __shfl_down(s, off);
    __shared__ float pw[4];
    if (lane == 0) pw[wid] = s;
    __syncthreads();
    if (threadIdx.x == 0)
        partial[blockIdx.x] = pw[0] + pw[1] + pw[2] + pw[3];
}

// ---------------- KL reduction: stage 2 --------------------------------------
__global__ __launch_bounds__(256) void kl_final(const float* __restrict__ partial,
                                                float* __restrict__ out)
{
    float s = 0.f;
    for (int i = threadIdx.x; i < KL_BLOCKS; i += 256) s += partial[i];
    #pragma unroll
    for (int off = 32; off > 0; off >>= 1)
        s += __shfl_down(s, off);
    __shared__ float pw[4];
    int wid = threadIdx.x >> 6;
    int lane = threadIdx.x & 63;
    if (lane == 0) pw[wid] = s;
    __syncthreads();
    if (threadIdx.x == 0)
        out[KL_IDX] = 0.5f * (pw[0] + pw[1] + pw[2] + pw[3]) / (float)M_TOT;
}

// ---------------- launcher ----------------------------------------------------
extern "C" void kernel_launch(void* const* d_in, const int* in_sizes, int n_in,
                              void* d_out, int out_size, void* d_ws, size_t ws_size,
                              hipStream_t stream)
{
    const float* events   = (const float*)d_in[0];
    const float* contexts = (const float*)d_in[1];
    const float* Wzm = (const float*)d_in[2];
    const float* bzm = (const float*)d_in[3];
    const float* Wzv = (const float*)d_in[4];
    const float* bzv = (const float*)d_in[5];
    const float* Wqm = (const float*)d_in[6];
    const float* bqm = (const float*)d_in[7];
    const float* Wqv = (const float*)d_in[8];
    const float* bqv = (const float*)d_in[9];
    float* out = (float*)d_out;

    u16*   wt      = (u16*)((char*)d_ws + WS_WT_OFF);
    float* bias    = (float*)((char*)d_ws + WS_BIAS_OFF);
    float* partial = (float*)((char*)d_ws + WS_PART_OFF);

    prep_kernel<<<512, 256, 0, stream>>>(Wzm, bzm, Wzv, bzv, Wqm, bqm, Wqv, bqv,
                                         wt, bias);
    gemm_kernel<<<1024, 256, 0, stream>>>(events, contexts, wt, bias, out);
    kl_kernel<<<KL_BLOCKS, 256, 0, stream>>>(out, partial);
    kl_final<<<1, 256, 0, stream>>>(partial, out);
}

// Round 12
// 125.407 us; speedup vs baseline: 1.1438x; 1.1438x over previous
//
#include <hip/hip_runtime.h>
#include <stdint.h>

typedef unsigned short u16;
typedef __attribute__((ext_vector_type(8))) short short8;
typedef __attribute__((ext_vector_type(4))) float f32x4;

#define B_      16
#define L_      1024
#define H_      1024
#define G_      128
#define M_TOT   16368            // B*(L-1)
#define OUT_SEG 2095104          // M_TOT*G_
#define KL_IDX  (4*OUT_SEG)
#define KL_BLOCKS 4092           // M_TOT / 4 exactly

// ws layout
#define WS_WT12_OFF  0           // bf16 [1024][1024] = 2,097,152 B
#define WS_W3T_OFF   2097152     // bf16 [256][1024]  =   524,288 B
#define WS_BIAS_OFF  2621440     // float[512]
#define WS_PART_OFF  2623488     // float[4092]

__device__ inline u16 f2bf(float f) {
    union { float f; uint32_t u; } x; x.f = f;
    uint32_t u = x.u;
    return (u16)((u + 0x7fffu + ((u >> 16) & 1u)) >> 16);
}

__device__ inline void gload16(const void* g, void* l) {
    __builtin_amdgcn_global_load_lds(
        (const __attribute__((address_space(1))) void*)g,
        (__attribute__((address_space(3))) void*)l, 16, 0, 0);
}

__device__ inline short8 cvt8(f32x4 x, f32x4 y) {
    union { short8 s; uint32_t u[4]; } r;
    asm("v_cvt_pk_bf16_f32 %0, %1, %2" : "=v"(r.u[0]) : "v"(x[0]), "v"(x[1]));
    asm("v_cvt_pk_bf16_f32 %0, %1, %2" : "=v"(r.u[1]) : "v"(x[2]), "v"(x[3]));
    asm("v_cvt_pk_bf16_f32 %0, %1, %2" : "=v"(r.u[2]) : "v"(y[0]), "v"(y[1]));
    asm("v_cvt_pk_bf16_f32 %0, %1, %2" : "=v"(r.u[3]) : "v"(y[2]), "v"(y[3]));
    return r.s;
}

// ---------------- prep: WT12 bf16 [1024][1024], W3T bf16 [256][1024], bias ---
// WT12 row n: n<512 -> W' col n over k in [0,1024); n>=512 -> col n-512 over
// k in [1024,2048). W3T row n2 -> Wq* col over k in [2048,3072).
__global__ __launch_bounds__(256) void prep_kernel(
    const float* __restrict__ Wzm, const float* __restrict__ bzm,
    const float* __restrict__ Wzv, const float* __restrict__ bzv,
    const float* __restrict__ Wqm, const float* __restrict__ bqm,
    const float* __restrict__ Wqv, const float* __restrict__ bqv,
    u16* __restrict__ wt12, u16* __restrict__ w3t, float* __restrict__ bias)
{
    int n = blockIdx.x;
    int tid = threadIdx.x;
    if (n < 1024) {
        int half = n >> 9;           // 0: k in [0,1024), 1: [1024,2048)
        int np   = n & 511;
        const float* W; const float* bsrc; int g;
        if (np < 128)      { W = Wzm; bsrc = bzm; g = np; }
        else if (np < 256) { W = Wzv; bsrc = bzv; g = np - 128; }
        else if (np < 384) { W = Wqm; bsrc = bqm; g = np - 256; }
        else               { W = Wqv; bsrc = bqv; g = np - 384; }
        if (half == 0 && tid == 0) bias[np] = bsrc[g];
        #pragma unroll
        for (int i = 0; i < 4; ++i) {
            int k = i * 256 + tid;
            wt12[(size_t)n * 1024 + k] =
                f2bf(W[(size_t)(half * 1024 + k) * G_ + g]);
        }
    } else {
        int n2 = n - 1024;           // 0..255
        const float* W = (n2 < 128) ? Wqm : Wqv;
        int g = n2 & 127;
        #pragma unroll
        for (int i = 0; i < 4; ++i) {
            int k = i * 256 + tid;
            w3t[(size_t)n2 * 1024 + k] =
                f2bf(W[(size_t)(2048 + k) * G_ + g]);
        }
    }
}

// ---------------- GEMM + combine ---------------------------------------------
// Block: 128 event rows [e0, e0+128), e0 = mt*127 (overlap 1 row), 128 vcols:
// v<64 -> G1 col nbg*64+v, v>=64 -> G2 col nbg*64+(v-64). 4 waves 2x2 of 64x64.
// Loop1 (32 steps): events x WT12. Loop2 (nbg>=4, 32 steps): contexts x W3T
// accumulated into the wn==0 (H1) accumulators. Epilogue: H2 -> LDS, then
// out[p][gcol] = H1[r] + H2[r+1] + bias, p = e - (e>>10), skip t==1023, r==127.
// Swizzles (verified R9): A chunk^=(r&7); B slot^=((row>>1)&3).
__global__ __launch_bounds__(256, 3) void gemm_kernel(
    const float* __restrict__ events, const float* __restrict__ contexts,
    const u16* __restrict__ wt12, const u16* __restrict__ w3t,
    const float* __restrict__ bias, float* __restrict__ out)
{
    __shared__ __align__(16) char lds[49152];
// address macros (no pointer objects initialized from LDS addrspacecast --
// that form fails gfx950 codegen as a "static initializer")
#define AF(buf) ((float*)(lds + (buf) * 16384))
#define BS(buf) ((u16*)(lds + 32768 + (buf) * 8192))

    const int tid = threadIdx.x;
    const int nbg = blockIdx.x / 136;          // 136 = 17*8: same-mt blocks
    const int mt  = blockIdx.x - nbg * 136;    // share bid%8 -> same XCD
    if (mt >= 129) return;
    const int e0  = mt * 127;

    const int lane = tid & 63;
    const int w    = tid >> 6;
    const int wm   = (w >> 1) * 64;
    const int wn   = (w & 1) * 64;
    const int lr   = lane & 15;
    const int kg   = lane >> 4;

    // ---- A staging: 4 chunks/thread; c = it*256+tid -> r=c>>3, cs=(c&7)^(r&7)
    const float* a1base = events + (size_t)e0 * 1024;
    uint32_t aoffs[4];
    const float* a2ptr[4];
    #pragma unroll
    for (int it = 0; it < 4; ++it) {
        int c  = it * 256 + tid;
        int r  = c >> 3;
        int cs = (c & 7) ^ (r & 7);
        aoffs[it] = (uint32_t)(r * 1024 + cs * 4);
        int e = e0 + r;
        int p = e - (e >> 10);
        a2ptr[it] = contexts + (size_t)p * 1024 + cs * 4;
    }
    // ---- B1 staging: 2 chunks/thread; c -> vrow=c>>2, ss=(c&3)^((v>>1)&3)
    const u16* b1[2];
    #pragma unroll
    for (int it = 0; it < 2; ++it) {
        int c  = it * 256 + tid;
        int v  = c >> 2;
        int ss = (c & 3) ^ ((v >> 1) & 3);
        int sr = (v < 64) ? (nbg * 64 + v) : (512 + nbg * 64 + (v - 64));
        b1[it] = wt12 + (size_t)sr * 1024 + ss * 8;
    }
    // ---- B2 staging (loop2): 1 chunk/thread over 64 rows
    const int v2  = tid >> 2;
    const int ss2 = (tid & 3) ^ ((v2 >> 1) & 3);
    const int nb2 = (nbg >= 4) ? (nbg - 4) : 0;
    const u16* b2 = w3t + (size_t)(nb2 * 64 + v2) * 1024 + ss2 * 8;

    // ---- fragment read offsets ----
    int aoff[4][2], boff[4];
    #pragma unroll
    for (int i = 0; i < 4; ++i) {
        int row = wm + i * 16 + lr;
        aoff[i][0] = row * 32 + (((2 * kg)     ^ (row & 7)) << 2);
        aoff[i][1] = row * 32 + (((2 * kg + 1) ^ (row & 7)) << 2);
        int nn = wn + i * 16 + lr;
        boff[i] = nn * 32 + ((kg ^ ((nn >> 1) & 3)) << 3);
    }

    f32x4 acc[4][4];
    #pragma unroll
    for (int i = 0; i < 4; ++i)
        #pragma unroll
        for (int j = 0; j < 4; ++j)
            acc[i][j] = (f32x4){0.f, 0.f, 0.f, 0.f};

    auto stage1 = [&](int buf, int kt) {
        int k0 = kt * 32;
        #pragma unroll
        for (int it = 0; it < 4; ++it)
            gload16(a1base + aoffs[it] + k0, AF(buf) + (it * 256 + tid) * 4);
        #pragma unroll
        for (int it = 0; it < 2; ++it)
            gload16(b1[it] + k0, BS(buf) + (it * 256 + tid) * 8);
    };
    auto stage2 = [&](int buf, int kt) {
        int k0 = kt * 32;
        #pragma unroll
        for (int it = 0; it < 4; ++it)
            gload16(a2ptr[it] + k0, AF(buf) + (it * 256 + tid) * 4);
        gload16(b2 + k0, BS(buf) + tid * 8);
    };
    auto compute = [&](int buf) {
        const float* Ab = AF(buf);
        const u16*   Bb = BS(buf);
        short8 a[4], bf[4];
        #pragma unroll
        for (int i = 0; i < 4; ++i) {
            f32x4 x = *(const f32x4*)&Ab[aoff[i][0]];
            f32x4 y = *(const f32x4*)&Ab[aoff[i][1]];
            a[i] = cvt8(x, y);
        }
        #pragma unroll
        for (int j = 0; j < 4; ++j)
            bf[j] = *(const short8*)&Bb[boff[j]];
        __builtin_amdgcn_s_setprio(1);
        #pragma unroll
        for (int i = 0; i < 4; ++i)
            #pragma unroll
            for (int j = 0; j < 4; ++j)
                acc[i][j] = __builtin_amdgcn_mfma_f32_16x16x32_bf16(
                    a[i], bf[j], acc[i][j], 0, 0, 0);
        __builtin_amdgcn_s_setprio(0);
    };

    // ---- loop 1: events x WT12 (32 steps) ----
    stage1(0, 0);
    __syncthreads();
    for (int kt = 0; kt < 32; ++kt) {
        if (kt + 1 < 32) stage1((kt + 1) & 1, kt + 1);
        compute(kt & 1);
        __syncthreads();
    }

    // ---- loop 2: contexts x W3T into H1 accs (q-column blocks only) ----
    if (nbg >= 4) {
        stage2(0, 0);
        __syncthreads();
        for (int kt = 0; kt < 32; ++kt) {
            if (kt + 1 < 32) stage2((kt + 1) & 1, kt + 1);
            if (wn == 0) compute(kt & 1);
            __syncthreads();
        }
    }

    // ---- epilogue: bounce H2 through LDS, combine, store ----
    float* h2lds = (float*)lds;                 // [128][68]
    __syncthreads();   // ensure all LDS staging traffic is done before reuse
    if (wn == 64) {
        #pragma unroll
        for (int i = 0; i < 4; ++i)
            #pragma unroll
            for (int j = 0; j < 4; ++j)
                #pragma unroll
                for (int rr = 0; rr < 4; ++rr) {
                    int r = wm + i * 16 + kg * 4 + rr;
                    h2lds[r * 68 + j * 16 + lr] = acc[i][j][rr];
                }
    }
    __syncthreads();
    if (wn == 0) {
        #pragma unroll
        for (int j = 0; j < 4; ++j) {
            int gcol = nbg * 64 + j * 16 + lr;
            int seg  = gcol >> 7;
            int col  = gcol & 127;
            float bv = bias[gcol];
            float* obase = out + (size_t)seg * OUT_SEG + col;
            #pragma unroll
            for (int i = 0; i < 4; ++i) {
                #pragma unroll
                for (int rr = 0; rr < 4; ++rr) {
                    int r = wm + i * 16 + kg * 4 + rr;
                    if (r == 127) continue;
                    int e = e0 + r;
                    if ((e & 1023) == 1023) continue;
                    int p = e - (e >> 10);
                    obase[(size_t)p * G_] =
                        acc[i][j][rr] + h2lds[(r + 1) * 68 + j * 16 + lr] + bv;
                }
            }
        }
    }
#undef AF
#undef BS
}

// ---------------- KL reduction: stage 1 --------------------------------------
__global__ __launch_bounds__(256) void kl_kernel(const float* __restrict__ out,
                                                 float* __restrict__ partial)
{
    int wid  = threadIdx.x >> 6;
    int row  = blockIdx.x * 4 + wid;        // M_TOT = 4092*4 exactly
    int lane = threadIdx.x & 63;
    const float* zm  = out;
    const float* zlv = out + OUT_SEG;
    const float* qm  = out + (size_t)2 * OUT_SEG;
    const float* qlv = out + (size_t)3 * OUT_SEG;
    size_t base = (size_t)row * G_;
    float s = 0.f;
    #pragma unroll
    for (int hh = 0; hh < 2; ++hh) {
        int g = lane + hh * 64;
        float a = zm[base + g], b = zlv[base + g];
        float c = qm[base + g], d = qlv[base + g];
        float diff = a - c;
        s += d - b + (__expf(b) + diff * diff) * __expf(-d) - 1.0f;
    }
    #pragma unroll
    for (int off = 32; off > 0; off >>= 1)
        s += __shfl_down(s, off);
    __shared__ float pw[4];
    if (lane == 0) pw[wid] = s;
    __syncthreads();
    if (threadIdx.x == 0)
        partial[blockIdx.x] = pw[0] + pw[1] + pw[2] + pw[3];
}

// ---------------- KL reduction: stage 2 --------------------------------------
__global__ __launch_bounds__(256) void kl_final(const float* __restrict__ partial,
                                                float* __restrict__ out)
{
    float s = 0.f;
    for (int i = threadIdx.x; i < KL_BLOCKS; i += 256) s += partial[i];
    #pragma unroll
    for (int off = 32; off > 0; off >>= 1)
        s += __shfl_down(s, off);
    __shared__ float pw[4];
    int wid = threadIdx.x >> 6;
    int lane = threadIdx.x & 63;
    if (lane == 0) pw[wid] = s;
    __syncthreads();
    if (threadIdx.x == 0)
        out[KL_IDX] = 0.5f * (pw[0] + pw[1] + pw[2] + pw[3]) / (float)M_TOT;
}

// ---------------- launcher ----------------------------------------------------
extern "C" void kernel_launch(void* const* d_in, const int* in_sizes, int n_in,
                              void* d_out, int out_size, void* d_ws, size_t ws_size,
                              hipStream_t stream)
{
    const float* events   = (const float*)d_in[0];
    const float* contexts = (const float*)d_in[1];
    const float* Wzm = (const float*)d_in[2];
    const float* bzm = (const float*)d_in[3];
    const float* Wzv = (const float*)d_in[4];
    const float* bzv = (const float*)d_in[5];
    const float* Wqm = (const float*)d_in[6];
    const float* bqm = (const float*)d_in[7];
    const float* Wqv = (const float*)d_in[8];
    const float* bqv = (const float*)d_in[9];
    float* out = (float*)d_out;

    u16*   wt12    = (u16*)((char*)d_ws + WS_WT12_OFF);
    u16*   w3t     = (u16*)((char*)d_ws + WS_W3T_OFF);
    float* bias    = (float*)((char*)d_ws + WS_BIAS_OFF);
    float* partial = (float*)((char*)d_ws + WS_PART_OFF);

    prep_kernel<<<1280, 256, 0, stream>>>(Wzm, bzm, Wzv, bzv, Wqm, bqm,
                                          Wqv, bqv, wt12, w3t, bias);
    gemm_kernel<<<1088, 256, 0, stream>>>(events, contexts, wt12, w3t,
                                          bias, out);
    kl_kernel<<<KL_BLOCKS, 256, 0, stream>>>(out, partial);
    kl_final<<<1, 256, 0, stream>>>(partial, out);
}